// Round 2
// baseline (85.419 us; speedup 1.0000x reference)
//
#include <hip/hip_runtime.h>

// CompressibleOgden: W = sum_k mu_k/alpha_k * (sum_i lamb_i^(alpha_k/2) - 3)
//                      + KAPPA/BETA^2 * (J^BETA - BETA*ln J - 1)
// lamb = eigvals of Cb = J^(-2/3) * F^T F,  J = sqrt(det(F^T F)) = |det F|
// KAPPA=100, BETA=2 are reference compile-time constants.

#define BLOCK 256

__global__ __launch_bounds__(BLOCK) void ogden_kernel(
    const float* __restrict__ F,
    const float* __restrict__ mu,
    const float* __restrict__ alpha,
    float* __restrict__ out, int n)
{
    __shared__ float sF[BLOCK * 9];

    const int tid  = threadIdx.x;
    const int base = blockIdx.x * BLOCK;          // first point of this block

    // ---- coalesced global -> LDS staging (9 floats/point, linear order) ----
    long long gbase = (long long)base * 9;
    int limit = (n - base) * 9;                   // valid floats this block
    if (limit > BLOCK * 9) limit = BLOCK * 9;
    #pragma unroll
    for (int j = 0; j < 9; ++j) {
        int idx = j * BLOCK + tid;
        if (idx < limit) sF[idx] = F[gbase + idx];
    }
    __syncthreads();

    const int i = base + tid;
    if (i >= n) return;

    // stride-9 LDS reads: gcd(9,32)=1 -> 2 lanes/bank in wave64 -> conflict-free
    const float* f = &sF[tid * 9];
    const float f00 = f[0], f01 = f[1], f02 = f[2];
    const float f10 = f[3], f11 = f[4], f12 = f[5];
    const float f20 = f[6], f21 = f[7], f22 = f[8];

    // ---- C = F^T F (symmetric) ----
    const float c00 = f00*f00 + f10*f10 + f20*f20;
    const float c01 = f00*f01 + f10*f11 + f20*f21;
    const float c02 = f00*f02 + f10*f12 + f20*f22;
    const float c11 = f01*f01 + f11*f11 + f21*f21;
    const float c12 = f01*f02 + f11*f12 + f21*f22;
    const float c22 = f02*f02 + f12*f12 + f22*f22;

    // ---- J = |det F| == sqrt(det C) ----
    const float detF = f00*(f11*f22 - f12*f21)
                     - f01*(f10*f22 - f12*f20)
                     + f02*(f10*f21 - f11*f20);
    const float J   = fabsf(detF);
    const float lnJ = __logf(J);

    // ---- Cb = J^(-2/3) * C ----
    const float s = __expf(-(2.0f/3.0f) * lnJ);
    const float b00 = s*c00, b01 = s*c01, b02 = s*c02;
    const float b11 = s*c11, b12 = s*c12, b22 = s*c22;

    // ---- eigenvalues of symmetric 3x3 (trigonometric method) ----
    const float q  = (b00 + b11 + b22) * (1.0f/3.0f);
    const float d0 = b00 - q, d1 = b11 - q, d2 = b22 - q;
    const float p2 = d0*d0 + d1*d1 + d2*d2
                   + 2.0f*(b01*b01 + b02*b02 + b12*b12);
    const float p  = sqrtf(p2 * (1.0f/6.0f));
    const float invp = (p > 1e-20f) ? (1.0f/p) : 0.0f;

    const float m00 = d0*invp, m01 = b01*invp, m02 = b02*invp;
    const float m11 = d1*invp, m12 = b12*invp, m22 = d2*invp;
    const float detB = m00*(m11*m22 - m12*m12)
                     - m01*(m01*m22 - m12*m02)
                     + m02*(m01*m12 - m11*m02);
    float r = 0.5f * detB;
    r = fminf(1.0f, fmaxf(-1.0f, r));

    const float phi = acosf(r) * (1.0f/3.0f);
    const float twop = 2.0f * p;
    float l1 = q + twop * __cosf(phi);
    float l3 = q + twop * __cosf(phi + 2.0943951023931953f); // + 2*pi/3
    float l2 = 3.0f*q - l1 - l3;

    l1 = fmaxf(l1, 1e-12f);
    l2 = fmaxf(l2, 1e-12f);
    l3 = fmaxf(l3, 1e-12f);

    const float lg1 = log2f(l1);
    const float lg2 = log2f(l2);
    const float lg3 = log2f(l3);

    // ---- W_iso = sum_k mu_k/alpha_k * (sum_i l_i^(alpha_k/2) - 3) ----
    float W = 0.0f;
    #pragma unroll
    for (int k = 0; k < 3; ++k) {
        const float ak = alpha[k];
        const float a2 = 0.5f * ak;
        const float pw = exp2f(a2 * lg1) + exp2f(a2 * lg2) + exp2f(a2 * lg3);
        W += (mu[k] / ak) * (pw - 3.0f);
    }

    // ---- W_vol, KAPPA=100, BETA=2: 25*(J^2 - 2 lnJ - 1) ----
    W += 25.0f * (J*J - 2.0f*lnJ - 1.0f);

    out[i] = W;
}

extern "C" void kernel_launch(void* const* d_in, const int* in_sizes, int n_in,
                              void* d_out, int out_size, void* d_ws, size_t ws_size,
                              hipStream_t stream) {
    const float* F     = (const float*)d_in[0];
    const float* mu    = (const float*)d_in[1];
    const float* alpha = (const float*)d_in[2];
    float* out = (float*)d_out;
    const int n = out_size;                       // 1,000,000 points

    const int grid = (n + BLOCK - 1) / BLOCK;
    ogden_kernel<<<grid, BLOCK, 0, stream>>>(F, mu, alpha, out, n);
}

// Round 5
// 82.495 us; speedup vs baseline: 1.0354x; 1.0354x over previous
//
#include <hip/hip_runtime.h>

// CompressibleOgden: W = sum_k mu_k/alpha_k * (sum_i lamb_i^(alpha_k/2) - 3)
//                      + KAPPA/BETA^2 * (J^BETA - BETA*ln J - 1)
// lamb = eigvals of Cb = J^(-2/3) * F^T F,  J = sqrt(det(F^T F)) = |det F|
// KAPPA=100, BETA=2 compile-time constants per reference.
//
// R5: hardware transcendentals, spellings verified against clang 22 notes:
//   __builtin_amdgcn_logf   == v_log_f32  (log base 2)   <- NOT _log2f
//   __builtin_amdgcn_exp2f  == v_exp_f32  (exp base 2)   <- NOT _expf
// + fast acos polynomial (|err| < 7e-5 rad vs 0.935 abs tolerance).

#define BLOCK 256
#define LN2F 0.6931471805599453f

__device__ __forceinline__ float fast_acos(float x) {
    // Abramowitz-Stegun 4.4.45 style, |err| <= 6.8e-5 rad on [-1,1]
    const float ax = fabsf(x);
    const float t  = __builtin_amdgcn_sqrtf(1.0f - ax);
    const float p  = 1.5707288f + ax * (-0.2121144f + ax * (0.0742610f - ax * 0.0187293f));
    const float ac = t * p;
    return (x >= 0.0f) ? ac : (3.14159265358979f - ac);
}

__global__ __launch_bounds__(BLOCK) void ogden_kernel(
    const float* __restrict__ F,
    const float* __restrict__ mu,
    const float* __restrict__ alpha,
    float* __restrict__ out, int n)
{
    __shared__ float sF[BLOCK * 9];

    const int tid  = threadIdx.x;
    const int base = blockIdx.x * BLOCK;

    // ---- coalesced global -> LDS staging (9 floats/point, linear order) ----
    long long gbase = (long long)base * 9;
    int limit = (n - base) * 9;
    if (limit > BLOCK * 9) limit = BLOCK * 9;
    #pragma unroll
    for (int j = 0; j < 9; ++j) {
        int idx = j * BLOCK + tid;
        if (idx < limit) sF[idx] = F[gbase + idx];
    }
    __syncthreads();

    const int i = base + tid;
    if (i >= n) return;

    // stride-9 LDS reads: gcd(9,32)=1 -> 2 lanes/bank in wave64 -> conflict-free
    const float* f = &sF[tid * 9];
    const float f00 = f[0], f01 = f[1], f02 = f[2];
    const float f10 = f[3], f11 = f[4], f12 = f[5];
    const float f20 = f[6], f21 = f[7], f22 = f[8];

    // ---- C = F^T F (symmetric) ----
    const float c00 = f00*f00 + f10*f10 + f20*f20;
    const float c01 = f00*f01 + f10*f11 + f20*f21;
    const float c02 = f00*f02 + f10*f12 + f20*f22;
    const float c11 = f01*f01 + f11*f11 + f21*f21;
    const float c12 = f01*f02 + f11*f12 + f21*f22;
    const float c22 = f02*f02 + f12*f12 + f22*f22;

    // ---- J = |det F| == sqrt(det C) ----
    const float detF = f00*(f11*f22 - f12*f21)
                     - f01*(f10*f22 - f12*f20)
                     + f02*(f10*f21 - f11*f20);
    const float J     = fabsf(detF);
    const float log2J = __builtin_amdgcn_logf(J);   // log2(J)
    const float lnJ   = log2J * LN2F;

    // ---- Cb = J^(-2/3) * C  via exp2(-2/3 * log2 J) ----
    const float s = __builtin_amdgcn_exp2f(-(2.0f/3.0f) * log2J);
    const float b00 = s*c00, b01 = s*c01, b02 = s*c02;
    const float b11 = s*c11, b12 = s*c12, b22 = s*c22;

    // ---- eigenvalues of symmetric 3x3 (trigonometric method) ----
    const float q  = (b00 + b11 + b22) * (1.0f/3.0f);
    const float d0 = b00 - q, d1 = b11 - q, d2 = b22 - q;
    const float p2 = d0*d0 + d1*d1 + d2*d2
                   + 2.0f*(b01*b01 + b02*b02 + b12*b12);
    const float p  = __builtin_amdgcn_sqrtf(p2 * (1.0f/6.0f));
    const float invp = (p > 1e-20f) ? __builtin_amdgcn_rcpf(p) : 0.0f;

    const float m00 = d0*invp, m01 = b01*invp, m02 = b02*invp;
    const float m11 = d1*invp, m12 = b12*invp, m22 = d2*invp;
    const float detB = m00*(m11*m22 - m12*m12)
                     - m01*(m01*m22 - m12*m02)
                     + m02*(m01*m12 - m11*m02);
    float r = 0.5f * detB;
    r = fminf(1.0f, fmaxf(-1.0f, r));

    const float phi  = fast_acos(r) * (1.0f/3.0f);
    const float twop = 2.0f * p;
    float l1 = q + twop * __cosf(phi);
    float l3 = q + twop * __cosf(phi + 2.0943951023931953f); // + 2*pi/3
    float l2 = 3.0f*q - l1 - l3;

    l1 = fmaxf(l1, 1e-12f);
    l2 = fmaxf(l2, 1e-12f);
    l3 = fmaxf(l3, 1e-12f);

    const float lg1 = __builtin_amdgcn_logf(l1);
    const float lg2 = __builtin_amdgcn_logf(l2);
    const float lg3 = __builtin_amdgcn_logf(l3);

    // ---- W_iso = sum_k mu_k/alpha_k * (sum_i l_i^(alpha_k/2) - 3) ----
    float W = 0.0f;
    #pragma unroll
    for (int k = 0; k < 3; ++k) {
        const float ak = alpha[k];
        const float a2 = 0.5f * ak;
        const float pw = __builtin_amdgcn_exp2f(a2 * lg1)
                       + __builtin_amdgcn_exp2f(a2 * lg2)
                       + __builtin_amdgcn_exp2f(a2 * lg3);
        W += (mu[k] / ak) * (pw - 3.0f);
    }

    // ---- W_vol, KAPPA=100, BETA=2: 25*(J^2 - 2 lnJ - 1) ----
    W += 25.0f * (J*J - 2.0f*lnJ - 1.0f);

    out[i] = W;
}

extern "C" void kernel_launch(void* const* d_in, const int* in_sizes, int n_in,
                              void* d_out, int out_size, void* d_ws, size_t ws_size,
                              hipStream_t stream) {
    const float* F     = (const float*)d_in[0];
    const float* mu    = (const float*)d_in[1];
    const float* alpha = (const float*)d_in[2];
    float* out = (float*)d_out;
    const int n = out_size;

    const int grid = (n + BLOCK - 1) / BLOCK;
    ogden_kernel<<<grid, BLOCK, 0, stream>>>(F, mu, alpha, out, n);
}